// Round 12
// baseline (615.522 us; speedup 1.0000x reference)
//
#include <hip/hip_runtime.h>

#define NN 50000
#define NE 800000
#define IN_CH 128
#define HID 32
#define HEADS 8
#define HC 256          // HEADS*HID
#define OUT_CH 64
#define NEG_SLOPE 0.2f
#define SCAN_BLOCKS 196  // 196*256 = 50176 >= NN
#define DBINS 1024       // degree-sort bins (deg clamped; Poisson(16) max ~50)

typedef _Float16 half4 __attribute__((ext_vector_type(4)));
typedef _Float16 half8 __attribute__((ext_vector_type(8)));
typedef float    f32x4 __attribute__((ext_vector_type(4)));

// ---------------- counting sort (CSR by dst) ----------------

__global__ void hist_kernel(const int* __restrict__ dst, int* __restrict__ deg) {
    int e = blockIdx.x * blockDim.x + threadIdx.x;
    if (e < NE) atomicAdd(&deg[dst[e]], 1);
}

__global__ __launch_bounds__(256)
void scan_phase1(const int* __restrict__ deg, int* __restrict__ excl,
                 int* __restrict__ bsum) {
    __shared__ int sm[256];
    const int t = blockIdx.x * 256 + threadIdx.x;
    const int v = (t < NN) ? deg[t] : 0;
    sm[threadIdx.x] = v;
    __syncthreads();
    for (int off = 1; off < 256; off <<= 1) {
        int u = (threadIdx.x >= off) ? sm[threadIdx.x - off] : 0;
        __syncthreads();
        sm[threadIdx.x] += u;
        __syncthreads();
    }
    if (t < NN) excl[t] = sm[threadIdx.x] - v;
    if (threadIdx.x == 255) bsum[blockIdx.x] = sm[255];
}

__global__ __launch_bounds__(256)
void scan_phase2(const int* __restrict__ bsum, int* __restrict__ boff,
                 int* __restrict__ offsets) {
    __shared__ int sm[256];
    const int t = threadIdx.x;
    const int v = (t < SCAN_BLOCKS) ? bsum[t] : 0;
    sm[t] = v;
    __syncthreads();
    for (int off = 1; off < 256; off <<= 1) {
        int u = (t >= off) ? sm[t - off] : 0;
        __syncthreads();
        sm[t] += u;
        __syncthreads();
    }
    if (t < SCAN_BLOCKS) boff[t] = sm[t] - v;
    if (t == 255) offsets[NN] = sm[255];
}

__global__ __launch_bounds__(256)
void scan_phase3(const int* __restrict__ excl, const int* __restrict__ boff,
                 int* __restrict__ offsets, int* __restrict__ cursor) {
    const int t = blockIdx.x * 256 + threadIdx.x;
    if (t < NN) {
        int v = excl[t] + boff[blockIdx.x];
        offsets[t] = v;
        cursor[t]  = v;
    }
}

__global__ void scatter_kernel(const int* __restrict__ src,
                               const int* __restrict__ dst,
                               int* __restrict__ cursor, int* __restrict__ ssrc,
                               int* __restrict__ sdst) {
    int e = blockIdx.x * blockDim.x + threadIdx.x;
    if (e < NE) {
        int d = dst[e];
        int pos = atomicAdd(&cursor[d], 1);
        ssrc[pos] = src[e];
        sdst[pos] = d;
    }
}

// ---------------- degree sort (nodes grouped by degree for agg waves) ----------------

__global__ void deg_hist(const int* __restrict__ deg, int* __restrict__ dh) {
    int n = blockIdx.x * blockDim.x + threadIdx.x;
    if (n < NN) atomicAdd(&dh[min(deg[n], DBINS - 1)], 1);
}

__global__ __launch_bounds__(1024)
void deg_scan(const int* __restrict__ dh, int* __restrict__ dcur) {
    __shared__ int sm[DBINS];
    const int t = threadIdx.x;
    const int v = dh[t];
    sm[t] = v;
    __syncthreads();
    for (int off = 1; off < DBINS; off <<= 1) {
        int u = (t >= off) ? sm[t - off] : 0;
        __syncthreads();
        sm[t] += u;
        __syncthreads();
    }
    dcur[t] = sm[t] - v;   // exclusive
}

__global__ void deg_scatter(const int* __restrict__ deg, int* __restrict__ dcur,
                            int* __restrict__ order) {
    int n = blockIdx.x * blockDim.x + threadIdx.x;
    if (n < NN) {
        int b = min(deg[n], DBINS - 1);
        int pos = atomicAdd(&dcur[b], 1);
        order[pos] = n;
    }
}

// ---------------- fp16 prep ----------------

__global__ void cast_f32_f16(const float* __restrict__ in, _Float16* __restrict__ out,
                             int n8) {
    int i = blockIdx.x * blockDim.x + threadIdx.x;
    if (i >= n8) return;
    float4 a = ((const float4*)in)[i * 2];
    float4 b = ((const float4*)in)[i * 2 + 1];
    half8 h;
    h[0] = (_Float16)a.x; h[1] = (_Float16)a.y; h[2] = (_Float16)a.z; h[3] = (_Float16)a.w;
    h[4] = (_Float16)b.x; h[5] = (_Float16)b.y; h[6] = (_Float16)b.z; h[7] = (_Float16)b.w;
    ((half8*)out)[i] = h;
}

__global__ void transpose_cast(const float* __restrict__ W, _Float16* __restrict__ Wt,
                               int K, int N) {
    int i = blockIdx.x * blockDim.x + threadIdx.x;
    if (i >= K * N) return;
    int k = i / N, n = i - k * N;
    Wt[(size_t)n * K + k] = (_Float16)W[i];
}

// ---------------- MFMA fp16 GEMM (row-major C) ----------------
__global__ __launch_bounds__(256)
void gemm_mfma_h(const _Float16* __restrict__ A, const _Float16* __restrict__ Bt,
                 _Float16* __restrict__ C, int M, int N, int K) {
    __shared__ _Float16 Asl[64][136];
    __shared__ _Float16 Btl[64][136];
    const int tid  = threadIdx.x;
    const int wave = tid >> 6, lane = tid & 63;
    const int lr = lane & 15, lk = lane >> 4;
    const int bm = blockIdx.x * 64, bn = blockIdx.y * 64;
    const int sr = tid >> 2;
    const int ss = (tid & 3) * 32;

    f32x4 acc[4];
#pragma unroll
    for (int i = 0; i < 4; ++i) acc[i] = (f32x4){0.f, 0.f, 0.f, 0.f};

    for (int k0 = 0; k0 < K; k0 += 128) {
        {
            const int ar = bm + sr;
            half8 v0 = {}, v1 = {}, v2 = {}, v3 = {};
            if (ar < M) {
                const half8* ga = (const half8*)(A + (size_t)ar * K + k0 + ss);
                v0 = ga[0]; v1 = ga[1]; v2 = ga[2]; v3 = ga[3];
            }
            *(half8*)&Asl[sr][ss + 0]  = v0;
            *(half8*)&Asl[sr][ss + 8]  = v1;
            *(half8*)&Asl[sr][ss + 16] = v2;
            *(half8*)&Asl[sr][ss + 24] = v3;
            const half8* gb = (const half8*)(Bt + (size_t)(bn + sr) * K + k0 + ss);
            half8 w0 = gb[0], w1 = gb[1], w2 = gb[2], w3 = gb[3];
            *(half8*)&Btl[sr][ss + 0]  = w0;
            *(half8*)&Btl[sr][ss + 8]  = w1;
            *(half8*)&Btl[sr][ss + 16] = w2;
            *(half8*)&Btl[sr][ss + 24] = w3;
        }
        __syncthreads();
#pragma unroll
        for (int kk = 0; kk < 128; kk += 32) {
            half8 a = *(const half8*)&Asl[wave * 16 + lr][kk + lk * 8];
#pragma unroll
            for (int nt = 0; nt < 4; ++nt) {
                half8 b = *(const half8*)&Btl[nt * 16 + lr][kk + lk * 8];
                acc[nt] = __builtin_amdgcn_mfma_f32_16x16x32_f16(a, b, acc[nt], 0, 0, 0);
            }
        }
        __syncthreads();
    }
#pragma unroll
    for (int nt = 0; nt < 4; ++nt) {
        const int col = bn + nt * 16 + lr;
#pragma unroll
        for (int r = 0; r < 4; ++r) {
            const int m = bm + wave * 16 + lk * 4 + r;
            if (m < M) C[(size_t)m * N + col] = (_Float16)acc[nt][r];
        }
    }
}

// ---------------- MFMA fp16 GEMM (head-major C: [N/32][M][32]) ----------------
__global__ __launch_bounds__(256)
void gemm_mfma_hm(const _Float16* __restrict__ A, const _Float16* __restrict__ Bt,
                  _Float16* __restrict__ C, int M, int N, int K) {
    __shared__ _Float16 Asl[64][136];
    __shared__ _Float16 Btl[64][136];
    const int tid  = threadIdx.x;
    const int wave = tid >> 6, lane = tid & 63;
    const int lr = lane & 15, lk = lane >> 4;
    const int bm = blockIdx.x * 64, bn = blockIdx.y * 64;
    const int sr = tid >> 2;
    const int ss = (tid & 3) * 32;

    f32x4 acc[4];
#pragma unroll
    for (int i = 0; i < 4; ++i) acc[i] = (f32x4){0.f, 0.f, 0.f, 0.f};

    for (int k0 = 0; k0 < K; k0 += 128) {
        {
            const int ar = bm + sr;
            half8 v0 = {}, v1 = {}, v2 = {}, v3 = {};
            if (ar < M) {
                const half8* ga = (const half8*)(A + (size_t)ar * K + k0 + ss);
                v0 = ga[0]; v1 = ga[1]; v2 = ga[2]; v3 = ga[3];
            }
            *(half8*)&Asl[sr][ss + 0]  = v0;
            *(half8*)&Asl[sr][ss + 8]  = v1;
            *(half8*)&Asl[sr][ss + 16] = v2;
            *(half8*)&Asl[sr][ss + 24] = v3;
            const half8* gb = (const half8*)(Bt + (size_t)(bn + sr) * K + k0 + ss);
            half8 w0 = gb[0], w1 = gb[1], w2 = gb[2], w3 = gb[3];
            *(half8*)&Btl[sr][ss + 0]  = w0;
            *(half8*)&Btl[sr][ss + 8]  = w1;
            *(half8*)&Btl[sr][ss + 16] = w2;
            *(half8*)&Btl[sr][ss + 24] = w3;
        }
        __syncthreads();
#pragma unroll
        for (int kk = 0; kk < 128; kk += 32) {
            half8 a = *(const half8*)&Asl[wave * 16 + lr][kk + lk * 8];
#pragma unroll
            for (int nt = 0; nt < 4; ++nt) {
                half8 b = *(const half8*)&Btl[nt * 16 + lr][kk + lk * 8];
                acc[nt] = __builtin_amdgcn_mfma_f32_16x16x32_f16(a, b, acc[nt], 0, 0, 0);
            }
        }
        __syncthreads();
    }
#pragma unroll
    for (int nt = 0; nt < 4; ++nt) {
        const int col = bn + nt * 16 + lr;
        const int hh = col >> 5, cc = col & 31;
#pragma unroll
        for (int r = 0; r < 4; ++r) {
            const int m = bm + wave * 16 + lk * 4 + r;
            if (m < M) C[((size_t)hh * M + m) * 32 + cc] = (_Float16)acc[nt][r];
        }
    }
}

// ---------------- attention coefficients ----------------

__device__ __forceinline__ float lrelu(float x) { return x > 0.f ? x : NEG_SLOPE * x; }

__global__ void attcoef1(const _Float16* __restrict__ xsh, const float* __restrict__ att_s,
                         const float* __restrict__ att_d,
                         float* __restrict__ asn,      // [NN][8]
                         float* __restrict__ adn2,     // [NN][8]
                         float* __restrict__ pself1) { // [8][NN]
    int n = blockIdx.x * blockDim.x + threadIdx.x;
    int h = blockIdx.y;
    if (n >= NN) return;
    const _Float16* xp = xsh + ((size_t)h * NN + n) * 32;
    const float* sp = att_s + h * 32;
    const float* dp = att_d + h * 32;
    float as = 0.f, ad = 0.f;
#pragma unroll
    for (int i = 0; i < 4; ++i) {
        half8 v = *(const half8*)(xp + i * 8);
#pragma unroll
        for (int j = 0; j < 8; ++j) {
            float f = (float)v[j];
            as += f * sp[i * 8 + j];
            ad += f * dp[i * 8 + j];
        }
    }
    asn[(size_t)n * 8 + h]  = as;
    adn2[(size_t)n * 8 + h] = ad;
    pself1[(size_t)h * NN + n] = __expf(lrelu(as + ad));
}

__global__ void pedge1(const int* __restrict__ ssrc, const int* __restrict__ sdst,
                       const float* __restrict__ asn, const float* __restrict__ adn2,
                       float* __restrict__ p1) {
    int i = blockIdx.x * blockDim.x + threadIdx.x;
    if (i >= NE) return;
    int s = ssrc[i], d = sdst[i];
    float4 A0 = *(const float4*)(asn + (size_t)s * 8);
    float4 A1 = *(const float4*)(asn + (size_t)s * 8 + 4);
    float4 D0 = *(const float4*)(adn2 + (size_t)d * 8);
    float4 D1 = *(const float4*)(adn2 + (size_t)d * 8 + 4);
    p1[0 * NE + i] = __expf(lrelu(A0.x + D0.x));
    p1[1 * NE + i] = __expf(lrelu(A0.y + D0.y));
    p1[2 * NE + i] = __expf(lrelu(A0.z + D0.z));
    p1[3 * NE + i] = __expf(lrelu(A0.w + D0.w));
    p1[4 * NE + i] = __expf(lrelu(A1.x + D1.x));
    p1[5 * NE + i] = __expf(lrelu(A1.y + D1.y));
    p1[6 * NE + i] = __expf(lrelu(A1.z + D1.z));
    p1[7 * NE + i] = __expf(lrelu(A1.w + D1.w));
}

__global__ void attcoef2(const _Float16* __restrict__ xs, const float* __restrict__ att_s,
                         const float* __restrict__ att_d,
                         float* __restrict__ a_s, float* __restrict__ a_d,
                         float* __restrict__ pself2) {
    int n = blockIdx.x * blockDim.x + threadIdx.x;
    if (n >= NN) return;
    const _Float16* xp = xs + (long)n * 64;
    float as = 0.f, ad = 0.f;
#pragma unroll
    for (int i = 0; i < 8; ++i) {
        half8 v = *(const half8*)(xp + i * 8);
#pragma unroll
        for (int j = 0; j < 8; ++j) {
            float f = (float)v[j];
            as += f * att_s[i * 8 + j];
            ad += f * att_d[i * 8 + j];
        }
    }
    a_s[n] = as;
    a_d[n] = ad;
    pself2[n] = __expf(lrelu(as + ad));
}

__global__ void pedge2(const int* __restrict__ ssrc, const int* __restrict__ sdst,
                       const float* __restrict__ a_s, const float* __restrict__ a_d,
                       float* __restrict__ p2) {
    int i = blockIdx.x * blockDim.x + threadIdx.x;
    if (i >= NE) return;
    p2[i] = __expf(lrelu(a_s[ssrc[i]] + a_d[sdst[i]]));
}

// ---------------- aggregation ----------------
// Degree-sorted `order` makes all slots in a wave near-equal degree
// (kills the 62% ballot-loop skew). agg1: 16 slots x 4 lanes x half8.

__global__ __launch_bounds__(256)
void agg1(const _Float16* __restrict__ xsh,   // [8][NN][32]
          const float* __restrict__ p1,       // [8][NE]
          const float* __restrict__ pself1,   // [8][NN]
          const int* __restrict__ offsets, const int* __restrict__ ssrc,
          const int* __restrict__ order,
          const float* __restrict__ bias,
          _Float16* __restrict__ out) {       // [NN][256]
    const int head = blockIdx.x & 7;
    const int grp  = blockIdx.x >> 3;
    const int wave = threadIdx.x >> 6;
    const int lane = threadIdx.x & 63;
    const int slot = lane >> 2;          // 16 slots/wave
    const int j8   = (lane & 3) * 8;     // 8 channels/lane
    const int idx  = grp * 64 + wave * 16 + slot;
    const bool valid = (idx < NN);
    const int n = valid ? order[idx] : 0;
    const _Float16* xh = xsh + (size_t)head * NN * 32;
    const float* pe = p1 + (size_t)head * NE;

    int beg = 0, end = 0;
    if (valid) { beg = offsets[n]; end = offsets[n + 1]; }
    float den = 0.f;
    float c[8] = {};
    int e = beg;
    while (__ballot(e < end) != 0ull) {
        const bool a0 = e < end, a1 = e + 1 < end, a2 = e + 2 < end, a3 = e + 3 < end;
        const int s0 = ssrc[a0 ? e : 0],     s1 = ssrc[a1 ? e + 1 : 0];
        const int s2 = ssrc[a2 ? e + 2 : 0], s3 = ssrc[a3 ? e + 3 : 0];
        const float q0 = a0 ? pe[e] : 0.f,     q1 = a1 ? pe[e + 1] : 0.f;
        const float q2 = a2 ? pe[e + 2] : 0.f, q3 = a3 ? pe[e + 3] : 0.f;
        half8 v0 = *(const half8*)(xh + (size_t)s0 * 32 + j8);
        half8 v1 = *(const half8*)(xh + (size_t)s1 * 32 + j8);
        half8 v2 = *(const half8*)(xh + (size_t)s2 * 32 + j8);
        half8 v3 = *(const half8*)(xh + (size_t)s3 * 32 + j8);
        den += (q0 + q1) + (q2 + q3);
#pragma unroll
        for (int q = 0; q < 8; ++q)
            c[q] += q0 * (float)v0[q] + q1 * (float)v1[q]
                  + q2 * (float)v2[q] + q3 * (float)v3[q];
        e += 4;
    }
    if (valid) {
        const float ps = pself1[(size_t)head * NN + n];
        half8 sv = *(const half8*)(xh + (size_t)n * 32 + j8);
        den += ps;
#pragma unroll
        for (int q = 0; q < 8; ++q) c[q] += ps * (float)sv[q];
        const float inv = 1.0f / den;
        half8 ho;
#pragma unroll
        for (int q = 0; q < 8; ++q) {
            float o = c[q] * inv + bias[head * 32 + j8 + q];
            o = o > 0.f ? o : expm1f(o);
            ho[q] = (_Float16)o;
        }
        *(half8*)(out + (size_t)n * HC + head * 32 + j8) = ho;
    }
}

// layer 2: 8 slots x 8 lanes x half8 (128B row), degree-sorted, 4-edge unroll.
__global__ __launch_bounds__(256)
void agg2(const _Float16* __restrict__ xs,    // [NN][64]
          const float* __restrict__ p2,       // [NE]
          const float* __restrict__ pself2,   // [NN]
          const int* __restrict__ offsets, const int* __restrict__ ssrc,
          const int* __restrict__ order,
          const float* __restrict__ bias,
          float* __restrict__ out) {          // [NN][64]
    const int grp  = blockIdx.x;
    const int wave = threadIdx.x >> 6;
    const int lane = threadIdx.x & 63;
    const int slot = lane >> 3;
    const int j8   = (lane & 7) * 8;
    const int idx  = grp * 32 + wave * 8 + slot;
    const bool valid = (idx < NN);
    const int n = valid ? order[idx] : 0;

    int beg = 0, end = 0;
    if (valid) { beg = offsets[n]; end = offsets[n + 1]; }
    float den = 0.f;
    float c[8] = {};
    int e = beg;
    while (__ballot(e < end) != 0ull) {
        const bool a0 = e < end, a1 = e + 1 < end, a2 = e + 2 < end, a3 = e + 3 < end;
        const int s0 = ssrc[a0 ? e : 0],     s1 = ssrc[a1 ? e + 1 : 0];
        const int s2 = ssrc[a2 ? e + 2 : 0], s3 = ssrc[a3 ? e + 3 : 0];
        const float q0 = a0 ? p2[e] : 0.f,     q1 = a1 ? p2[e + 1] : 0.f;
        const float q2 = a2 ? p2[e + 2] : 0.f, q3 = a3 ? p2[e + 3] : 0.f;
        half8 v0 = *(const half8*)(xs + (size_t)s0 * OUT_CH + j8);
        half8 v1 = *(const half8*)(xs + (size_t)s1 * OUT_CH + j8);
        half8 v2 = *(const half8*)(xs + (size_t)s2 * OUT_CH + j8);
        half8 v3 = *(const half8*)(xs + (size_t)s3 * OUT_CH + j8);
        den += (q0 + q1) + (q2 + q3);
#pragma unroll
        for (int q = 0; q < 8; ++q)
            c[q] += q0 * (float)v0[q] + q1 * (float)v1[q]
                  + q2 * (float)v2[q] + q3 * (float)v3[q];
        e += 4;
    }
    if (valid) {
        const float ps = pself2[n];
        half8 sv = *(const half8*)(xs + (size_t)n * OUT_CH + j8);
        den += ps;
#pragma unroll
        for (int q = 0; q < 8; ++q) c[q] += ps * (float)sv[q];
        const float inv = 1.0f / den;
        float4 w0, w1;
        w0.x = c[0] * inv + bias[j8 + 0];
        w0.y = c[1] * inv + bias[j8 + 1];
        w0.z = c[2] * inv + bias[j8 + 2];
        w0.w = c[3] * inv + bias[j8 + 3];
        w1.x = c[4] * inv + bias[j8 + 4];
        w1.y = c[5] * inv + bias[j8 + 5];
        w1.z = c[6] * inv + bias[j8 + 6];
        w1.w = c[7] * inv + bias[j8 + 7];
        *(float4*)(out + (size_t)n * OUT_CH + j8)     = w0;
        *(float4*)(out + (size_t)n * OUT_CH + j8 + 4) = w1;
    }
}

// ---------------- launch ----------------

extern "C" void kernel_launch(void* const* d_in, const int* in_sizes, int n_in,
                              void* d_out, int out_size, void* d_ws, size_t ws_size,
                              hipStream_t stream) {
    const float* x     = (const float*)d_in[0];
    const int*   ei    = (const int*)d_in[1];      // int32 edge index [2, E]
    const float* W1    = (const float*)d_in[2];
    const float* atts1 = (const float*)d_in[3];
    const float* attd1 = (const float*)d_in[4];
    const float* bias1 = (const float*)d_in[5];
    const float* W2    = (const float*)d_in[6];
    const float* atts2 = (const float*)d_in[7];
    const float* attd2 = (const float*)d_in[8];
    const float* bias2 = (const float*)d_in[9];
    float*       out   = (float*)d_out;

    const int* srcp = ei;
    const int* dstp = ei + NE;

    char* ws = (char*)d_ws;
    size_t off = 0;
    auto alloc = [&](size_t bytes) -> void* {
        void* p = ws + off;
        off += (bytes + 255) & ~(size_t)255;
        return p;
    };
    _Float16* xh     = (_Float16*)alloc((size_t)NN * IN_CH * 2);   // 12.8 MB
    _Float16* xsh1   = (_Float16*)alloc((size_t)NN * HC * 2);      // 25.6 MB head-major
    _Float16* h1h    = (_Float16*)alloc((size_t)NN * HC * 2);      // 25.6 MB row-major
    float*    p1     = (float*)alloc((size_t)HEADS * NE * 4);      // 25.6 MB
    _Float16* W1t    = (_Float16*)alloc((size_t)HC * IN_CH * 2);
    _Float16* W2t    = (_Float16*)alloc((size_t)OUT_CH * HC * 2);
    float*    asn    = (float*)alloc((size_t)NN * 8 * 4);
    float*    adn2   = (float*)alloc((size_t)NN * 8 * 4);
    float*    pself1 = (float*)alloc((size_t)HEADS * NN * 4);
    float*    as2    = (float*)alloc((size_t)NN * 4);
    float*    ad2    = (float*)alloc((size_t)NN * 4);
    float*    pself2 = (float*)alloc((size_t)NN * 4);
    float*    p2     = (float*)alloc((size_t)NE * 4);
    int*   deg      = (int*)alloc((size_t)NN * 4);
    int*   offsets  = (int*)alloc((size_t)(NN + 1) * 4);
    int*   cursor   = (int*)alloc((size_t)NN * 4);
    int*   ssrc     = (int*)alloc((size_t)NE * 4);
    int*   sdst     = (int*)alloc((size_t)NE * 4);
    int*   excl     = (int*)alloc((size_t)NN * 4);
    int*   bsum     = (int*)alloc((size_t)SCAN_BLOCKS * 4);
    int*   boff     = (int*)alloc((size_t)SCAN_BLOCKS * 4);
    int*   dh       = (int*)alloc((size_t)DBINS * 4);
    int*   dcur     = (int*)alloc((size_t)DBINS * 4);
    int*   order    = (int*)alloc((size_t)NN * 4);
    _Float16* xs2h = xsh1;   // layer-2 features alias (dead after agg1)

    // --- CSR build + degree sort ---
    hipMemsetAsync(deg, 0, (size_t)NN * 4, stream);
    hipMemsetAsync(dh, 0, (size_t)DBINS * 4, stream);
    hist_kernel<<<(NE + 255) / 256, 256, 0, stream>>>(dstp, deg);
    scan_phase1<<<SCAN_BLOCKS, 256, 0, stream>>>(deg, excl, bsum);
    scan_phase2<<<1, 256, 0, stream>>>(bsum, boff, offsets);
    scan_phase3<<<SCAN_BLOCKS, 256, 0, stream>>>(excl, boff, offsets, cursor);
    scatter_kernel<<<(NE + 255) / 256, 256, 0, stream>>>(srcp, dstp, cursor, ssrc, sdst);
    deg_hist<<<SCAN_BLOCKS, 256, 0, stream>>>(deg, dh);
    deg_scan<<<1, DBINS, 0, stream>>>(dh, dcur);
    deg_scatter<<<SCAN_BLOCKS, 256, 0, stream>>>(deg, dcur, order);

    // --- fp16 prep ---
    cast_f32_f16<<<(NN * IN_CH / 8 + 255) / 256, 256, 0, stream>>>(x, xh, NN * IN_CH / 8);
    transpose_cast<<<(IN_CH * HC + 255) / 256, 256, 0, stream>>>(W1, W1t, IN_CH, HC);
    transpose_cast<<<(HC * OUT_CH + 255) / 256, 256, 0, stream>>>(W2, W2t, HC, OUT_CH);

    // --- layer 1 ---
    {
        dim3 grid((NN + 63) / 64, HC / 64);
        gemm_mfma_hm<<<grid, 256, 0, stream>>>(xh, W1t, xsh1, NN, HC, IN_CH);
    }
    {
        dim3 grid((NN + 255) / 256, HEADS);
        attcoef1<<<grid, 256, 0, stream>>>(xsh1, atts1, attd1, asn, adn2, pself1);
    }
    pedge1<<<(NE + 255) / 256, 256, 0, stream>>>(ssrc, sdst, asn, adn2, p1);
    agg1<<<((NN + 63) / 64) * 8, 256, 0, stream>>>(xsh1, p1, pself1, offsets, ssrc,
                                                   order, bias1, h1h);

    // --- layer 2 ---
    {
        dim3 grid((NN + 63) / 64, OUT_CH / 64);
        gemm_mfma_h<<<grid, 256, 0, stream>>>(h1h, W2t, xs2h, NN, OUT_CH, HC);
    }
    attcoef2<<<(NN + 255) / 256, 256, 0, stream>>>(xs2h, atts2, attd2, as2, ad2, pself2);
    pedge2<<<(NE + 255) / 256, 256, 0, stream>>>(ssrc, sdst, as2, ad2, p2);
    agg2<<<(NN + 31) / 32, 256, 0, stream>>>(xs2h, p2, pself2, offsets, ssrc,
                                             order, bias2, out);
}